// Round 5
// baseline (319.357 us; speedup 1.0000x reference)
//
#include <hip/hip_runtime.h>
#include <math.h>

#define EPS 0.3f

typedef __attribute__((ext_vector_type(8))) short bf16x8;
typedef __attribute__((ext_vector_type(4))) short bf16x4;
typedef __attribute__((ext_vector_type(4))) float f32x4;

__device__ __forceinline__ short f2bf(float f) {
    union { float f; unsigned u; } v; v.f = f;
    unsigned r = v.u + 0x7FFFu + ((v.u >> 16) & 1u);  // RNE
    return (short)(r >> 16);
}

__global__ void deg_count_i(const int* __restrict__ dst, int* __restrict__ cnt, int E) {
    int i = blockIdx.x * blockDim.x + threadIdx.x;
    if (i < E) atomicAdd(&cnt[dst[i]], 1);
}

// per-block exclusive scan of cnt -> rs; block totals -> bsum
__global__ void scan_block(const int* __restrict__ cnt, int* __restrict__ rs,
                           int* __restrict__ bsum, int N) {
    __shared__ int tmp[256];
    int tid = threadIdx.x;
    int i = blockIdx.x * 256 + tid;
    int v = (i < N) ? cnt[i] : 0;
    tmp[tid] = v;
    __syncthreads();
    #pragma unroll
    for (int off = 1; off < 256; off <<= 1) {
        int other = (tid >= off) ? tmp[tid - off] : 0;
        __syncthreads();
        tmp[tid] += other;
        __syncthreads();
    }
    if (i < N) rs[i] = tmp[tid] - v;          // exclusive
    if (tid == 255) bsum[blockIdx.x] = tmp[tid];
}

// single-block exclusive scan of bsum (nb <= 1024), in place
__global__ void scan_top(int* __restrict__ bsum, int nb) {
    __shared__ int tmp[1024];
    int tid = threadIdx.x;
    int v = (tid < nb) ? bsum[tid] : 0;
    tmp[tid] = v;
    __syncthreads();
    #pragma unroll
    for (int off = 1; off < 1024; off <<= 1) {
        int other = (tid >= off) ? tmp[tid - off] : 0;
        __syncthreads();
        tmp[tid] += other;
        __syncthreads();
    }
    if (tid < nb) bsum[tid] = tmp[tid] - v;   // exclusive
}

// rs[i] += bsum[block]; cursor copy; rs[N] = E; fused d = rsqrt(max(deg,1))
__global__ void scan_add(int* __restrict__ rs, const int* __restrict__ bsum,
                         int* __restrict__ cur, const int* __restrict__ cnt,
                         float* __restrict__ d, int N, int E) {
    int i = blockIdx.x * 256 + threadIdx.x;
    if (i < N) {
        int v = rs[i] + bsum[blockIdx.x];
        rs[i] = v;
        cur[i] = v;
        d[i] = rsqrtf(fmaxf((float)cnt[i], 1.0f));
    }
    if (i == 0) rs[N] = E;
}

// counting-sort bucket fill; one aligned 8B store per edge: (src, dst)
__global__ void bucket_fill(const int* __restrict__ src, const int* __restrict__ dst,
                            int* __restrict__ cur, int2* __restrict__ est, int E) {
    int i = blockIdx.x * blockDim.x + threadIdx.x;
    if (i < E) {
        int t = dst[i];
        int p = atomicAdd(&cur[t], 1);
        int2 v; v.x = src[i]; v.y = t;
        est[p] = v;
    }
}

// w [64][256] fp32 -> bf16
__global__ void cvt_w(const float* __restrict__ w, short* __restrict__ wb) {
    int i = blockIdx.x * blockDim.x + threadIdx.x;
    if (i < 64 * 256) wb[i] = f2bf(w[i]);
}

// per-CSR-slot: epack = (src, coef) with coef = tanh(a[t]+b[s]+gb)*d[t]*d[s]
__global__ void edge_coef(const int2* __restrict__ est,
                          const float* __restrict__ a, const float* __restrict__ b,
                          const float* __restrict__ d, const float* __restrict__ gbp,
                          int layer, int2* __restrict__ epack, int E) {
    int i = blockIdx.x * blockDim.x + threadIdx.x;
    if (i < E) {
        int2 e = est[i];
        float c = tanhf(a[e.y] + b[e.x] + gbp[layer]) * d[e.y] * d[e.x];
        int2 o; o.x = e.x; o.y = __float_as_int(c);
        epack[i] = o;
    }
}

// x0 = relu(h @ w^T + b); fused layer-0 gate dots. LDS-staged A (coalesced).
// MFMA 16x16x32 bf16. A: [m=lane&15][k=quad*8+j]; D: col=lane&15, row=quad*4+reg.
#define LROW 264   // LDS row stride in shorts (256 + 8 pad): 528 B, 16B-aligned
__global__ __launch_bounds__(256) void t1_mfma(
    const float* __restrict__ h, const short* __restrict__ wb,
    const float* __restrict__ t1b, const float* __restrict__ gw,
    float* __restrict__ XA, float* __restrict__ ga, float* __restrict__ gbv, int N)
{
    __shared__ short lh[4][16 * LROW];
    int wave = threadIdx.x >> 6;
    int lane = threadIdx.x & 63;
    int l15 = lane & 15, quad = lane >> 4;
    int M0 = (blockIdx.x * 4 + wave) * 16;
    if (M0 >= N) return;
    int rlim = N - M0;                         // rows valid in this tile (<=16)

    short* myl = lh[wave];
    const float* hb = h + (size_t)M0 * 256;
    #pragma unroll
    for (int r = 0; r < 16; ++r) {
        if (r < rlim) {
            float4 v = *(const float4*)&hb[(size_t)r * 256 + lane * 4];
            bf16x4 sv;
            sv[0] = f2bf(v.x); sv[1] = f2bf(v.y); sv[2] = f2bf(v.z); sv[3] = f2bf(v.w);
            *(bf16x4*)&myl[r * LROW + lane * 4] = sv;
        }
    }

    f32x4 acc[4];
    #pragma unroll
    for (int nt = 0; nt < 4; ++nt) acc[nt] = (f32x4){0.f, 0.f, 0.f, 0.f};

    const short* wq = wb + quad * 8;
    #pragma unroll
    for (int kc = 0; kc < 256; kc += 32) {
        bf16x8 af = *(const bf16x8*)&myl[l15 * LROW + kc + quad * 8];
        #pragma unroll
        for (int nt = 0; nt < 4; ++nt) {
            bf16x8 bf = *(const bf16x8*)(wq + (size_t)(nt * 16 + l15) * 256 + kc);
            acc[nt] = __builtin_amdgcn_mfma_f32_16x16x32_bf16(af, bf, acc[nt], 0, 0, 0);
        }
    }

    float pa[4] = {0.f, 0.f, 0.f, 0.f};
    float pb[4] = {0.f, 0.f, 0.f, 0.f};
    #pragma unroll
    for (int nt = 0; nt < 4; ++nt) {
        int n = nt * 16 + l15;
        float bias = t1b[n];
        float gd = gw[n], gs = gw[64 + n];
        #pragma unroll
        for (int r = 0; r < 4; ++r) {
            int row = quad * 4 + r;
            if (row < rlim) {
                float x = fmaxf(acc[nt][r] + bias, 0.f);
                XA[(size_t)(M0 + row) * 64 + n] = x;
                pa[r] += x * gd;
                pb[r] += x * gs;
            }
        }
    }
    #pragma unroll
    for (int off = 1; off < 16; off <<= 1) {
        #pragma unroll
        for (int r = 0; r < 4; ++r) {
            pa[r] += __shfl_xor(pa[r], off, 64);
            pb[r] += __shfl_xor(pb[r], off, 64);
        }
    }
    if (l15 == 0) {
        #pragma unroll
        for (int r = 0; r < 4; ++r) {
            int row = quad * 4 + r;
            if (row < rlim) {
                ga[M0 + row] = pa[r];
                gbv[M0 + row] = pb[r];
            }
        }
    }
}

// One wave per dst node, 4 edge-groups x 16 feature-quads (float4/lane):
// x_next[t] = EPS*raw[t] + sum_e coef(e) * x_cur[src(e)];
// epack = (src, coef_bits): one 8B load per edge in the hot loop.
// Optionally fuses next layer's gate dots from the freshly computed row.
__global__ __launch_bounds__(256) void gather4(
    const int* __restrict__ rs, const int2* __restrict__ epack,
    const float* __restrict__ xc, const float* __restrict__ raw,
    float* __restrict__ xn, const float* __restrict__ gw_next,
    float* __restrict__ ga_next, float* __restrict__ gb_next, int N)
{
    int tid = threadIdx.x;
    int t = blockIdx.x * 4 + (tid >> 6);
    if (t >= N) return;
    int lane = tid & 63;
    int g = lane >> 4;        // edge group 0..3
    int q = lane & 15;        // feature quad; features 4q..4q+3
    int beg = rs[t], end = rs[t + 1];

    float ax = 0.f, ay = 0.f, az = 0.f, aw = 0.f;
    if (g == 0) {
        float4 rv = *(const float4*)&raw[(size_t)t * 64 + q * 4];
        ax = EPS * rv.x; ay = EPS * rv.y; az = EPS * rv.z; aw = EPS * rv.w;
    }

    int i = beg + g;
    // 2x unrolled: two independent edges in flight per group
    for (; i + 4 < end; i += 8) {
        int2 e0 = epack[i];
        int2 e1 = epack[i + 4];
        float c0 = __int_as_float(e0.y);
        float c1 = __int_as_float(e1.y);
        float4 x0 = *(const float4*)&xc[(size_t)e0.x * 64 + q * 4];
        float4 x1 = *(const float4*)&xc[(size_t)e1.x * 64 + q * 4];
        ax += c0 * x0.x + c1 * x1.x;
        ay += c0 * x0.y + c1 * x1.y;
        az += c0 * x0.z + c1 * x1.z;
        aw += c0 * x0.w + c1 * x1.w;
    }
    if (i < end) {
        int2 e0 = epack[i];
        float c0 = __int_as_float(e0.y);
        float4 x0 = *(const float4*)&xc[(size_t)e0.x * 64 + q * 4];
        ax += c0 * x0.x; ay += c0 * x0.y; az += c0 * x0.z; aw += c0 * x0.w;
    }

    // reduce across the 4 edge groups (lanes differing in bits 4,5)
    #pragma unroll
    for (int off = 16; off < 64; off <<= 1) {
        ax += __shfl_xor(ax, off, 64);
        ay += __shfl_xor(ay, off, 64);
        az += __shfl_xor(az, off, 64);
        aw += __shfl_xor(aw, off, 64);
    }
    if (g == 0) {
        float4 o; o.x = ax; o.y = ay; o.z = az; o.w = aw;
        *(float4*)&xn[(size_t)t * 64 + q * 4] = o;
    }

    if (gw_next) {
        float4 gd = *(const float4*)&gw_next[q * 4];
        float4 gs = *(const float4*)&gw_next[64 + q * 4];
        float av = ax * gd.x + ay * gd.y + az * gd.z + aw * gd.w;
        float bv = ax * gs.x + ay * gs.y + az * gs.z + aw * gs.w;
        #pragma unroll
        for (int off = 1; off < 16; off <<= 1) {
            av += __shfl_xor(av, off, 64);
            bv += __shfl_xor(bv, off, 64);
        }
        if (lane == 0) { ga_next[t] = av; gb_next[t] = bv; }
    }
}

// logits = x @ t2_w^T + t2_b, then log_softmax over 16; thread per node
__global__ void out_logsoftmax(const float* __restrict__ x, const float* __restrict__ w,
                               const float* __restrict__ b, float* __restrict__ out, int N) {
    int n = blockIdx.x * blockDim.x + threadIdx.x;
    if (n >= N) return;
    float xi[64];
    const float4* xr = (const float4*)&x[(size_t)n * 64];
    #pragma unroll
    for (int k = 0; k < 16; ++k) {
        float4 v = xr[k];
        xi[4 * k + 0] = v.x; xi[4 * k + 1] = v.y; xi[4 * k + 2] = v.z; xi[4 * k + 3] = v.w;
    }
    float logits[16];
    float mx = -1e30f;
    #pragma unroll
    for (int j = 0; j < 16; ++j) {
        const float4* wr = (const float4*)&w[j * 64];
        float acc = b[j];
        #pragma unroll
        for (int k = 0; k < 16; ++k) {
            float4 wv = wr[k];
            acc += xi[4 * k + 0] * wv.x + xi[4 * k + 1] * wv.y
                 + xi[4 * k + 2] * wv.z + xi[4 * k + 3] * wv.w;
        }
        logits[j] = acc;
        mx = fmaxf(mx, acc);
    }
    float sum = 0.0f;
    #pragma unroll
    for (int j = 0; j < 16; ++j) sum += expf(logits[j] - mx);
    float lse = mx + logf(sum);
    #pragma unroll
    for (int j = 0; j < 16; ++j) out[(size_t)n * 16 + j] = logits[j] - lse;
}

extern "C" void kernel_launch(void* const* d_in, const int* in_sizes, int n_in,
                              void* d_out, int out_size, void* d_ws, size_t ws_size,
                              hipStream_t stream) {
    const float* h    = (const float*)d_in[0];
    const int*   src  = (const int*)d_in[1];
    const int*   dst  = (const int*)d_in[2];
    const float* t1w  = (const float*)d_in[3];
    const float* t1b  = (const float*)d_in[4];
    const float* gw   = (const float*)d_in[5];   // [2, 128]
    const float* gbia = (const float*)d_in[6];   // [2]
    const float* t2w  = (const float*)d_in[7];   // [16, 64]
    const float* t2b  = (const float*)d_in[8];   // [16]
    float* out = (float*)d_out;

    const int N = in_sizes[0] / 256;
    const int E = in_sizes[1];
    const int NB = (N + 255) / 256;              // scan blocks (<=1024)

    char* p = (char*)d_ws;
    float* XA    = (float*)p;           p += (size_t)N * 64 * 4;   // x0 (raw) -> x2
    float* XB    = (float*)p;           p += (size_t)N * 64 * 4;   // x1
    float* dco   = (float*)p;           p += (size_t)N * 4;
    float* ga0   = (float*)p;           p += (size_t)N * 4;
    float* gb0   = (float*)p;           p += (size_t)N * 4;
    float* ga1   = (float*)p;           p += (size_t)N * 4;
    float* gb1   = (float*)p;           p += (size_t)N * 4;
    int*   cnt   = (int*)p;             p += (size_t)N * 4;
    int*   rs    = (int*)p;             p += (size_t)(N + 1) * 4;
    int*   cur   = (int*)p;             p += (size_t)N * 4;
    int*   bsum  = (int*)p;             p += 1024 * 4;
    p = (char*)(((size_t)p + 15) & ~(size_t)15);
    int2*  est   = (int2*)p;            p += (size_t)E * 8;        // (src, dst) CSR order
    int2*  epack = (int2*)p;            p += (size_t)E * 8;        // (src, coef)
    short* wbf   = (short*)p;

    // ---- CSR build (counting sort by dst) + degree norm ----
    hipMemsetAsync(cnt, 0, (size_t)N * 4, stream);
    deg_count_i<<<(E + 255) / 256, 256, 0, stream>>>(dst, cnt, E);
    scan_block<<<NB, 256, 0, stream>>>(cnt, rs, bsum, N);
    scan_top<<<1, 1024, 0, stream>>>(bsum, NB);
    scan_add<<<NB, 256, 0, stream>>>(rs, bsum, cur, cnt, dco, N, E);
    bucket_fill<<<(E + 255) / 256, 256, 0, stream>>>(src, dst, cur, est, E);

    // ---- t1 + relu (MFMA, LDS-staged) with fused layer-0 gate dots ----
    cvt_w<<<64, 256, 0, stream>>>(t1w, wbf);
    t1_mfma<<<(N + 63) / 64, 256, 0, stream>>>(h, wbf, t1b, gw, XA, ga0, gb0, N);

    // ---- layer 0 ----
    edge_coef<<<(E + 255) / 256, 256, 0, stream>>>(est, ga0, gb0, dco, gbia, 0, epack, E);
    gather4<<<(N + 3) / 4, 256, 0, stream>>>(rs, epack, XA, XA, XB, gw + 128, ga1, gb1, N);

    // ---- layer 1 ----
    edge_coef<<<(E + 255) / 256, 256, 0, stream>>>(est, ga1, gb1, dco, gbia, 1, epack, E);
    gather4<<<(N + 3) / 4, 256, 0, stream>>>(rs, epack, XB, XA, XA, nullptr, nullptr, nullptr, N);

    // ---- logits + log_softmax ----
    out_logsoftmax<<<(N + 255) / 256, 256, 0, stream>>>(XA, t2w, t2b, out, N);
}

// Round 6
// 276.361 us; speedup vs baseline: 1.1556x; 1.1556x over previous
//
#include <hip/hip_runtime.h>
#include <math.h>

#define EPS 0.3f

typedef __attribute__((ext_vector_type(8))) short bf16x8;
typedef __attribute__((ext_vector_type(4))) short bf16x4;
typedef __attribute__((ext_vector_type(4))) float f32x4;

__device__ __forceinline__ short f2bf(float f) {
    union { float f; unsigned u; } v; v.f = f;
    unsigned r = v.u + 0x7FFFu + ((v.u >> 16) & 1u);  // RNE
    return (short)(r >> 16);
}

// ---- CSR build: two-level binned counting sort (bins = dst>>8) ----

// per-block LDS histogram of dst>>8, merged into chist
__global__ __launch_bounds__(256) void coarse_hist(const int* __restrict__ dst,
                                                   int* __restrict__ chist, int E) {
    __shared__ int lh[256];
    lh[threadIdx.x] = 0;
    __syncthreads();
    for (int i = blockIdx.x * 256 + threadIdx.x; i < E; i += gridDim.x * 256)
        atomicAdd(&lh[dst[i] >> 8], 1);
    __syncthreads();
    int v = lh[threadIdx.x];
    if (v) atomicAdd(&chist[threadIdx.x], v);
}

// single-block exclusive scan of chist -> cbase, ccur; rs[N]=E
__global__ void coarse_scan(const int* __restrict__ chist, int* __restrict__ cbase,
                            int* __restrict__ ccur, int* __restrict__ rs,
                            int NBIN, int N, int E) {
    __shared__ int tmp[256];
    int tid = threadIdx.x;
    int v = (tid < NBIN) ? chist[tid] : 0;
    tmp[tid] = v;
    __syncthreads();
    #pragma unroll
    for (int off = 1; off < 256; off <<= 1) {
        int o = (tid >= off) ? tmp[tid - off] : 0;
        __syncthreads();
        tmp[tid] += o;
        __syncthreads();
    }
    if (tid < NBIN) { cbase[tid] = tmp[tid] - v; ccur[tid] = tmp[tid] - v; }
    if (tid == NBIN - 1) cbase[NBIN] = tmp[tid];
    if (tid == 0) rs[N] = E;
}

// partition edges into coarse-bin-grouped order: per-block LDS hist ->
// bulk range reservation -> grouped writes (good line locality)
__global__ __launch_bounds__(256) void partition(const int* __restrict__ src,
                                                 const int* __restrict__ dst,
                                                 int* __restrict__ ccur,
                                                 int2* __restrict__ part, int E) {
    __shared__ int lh[256];
    __shared__ int lbase[256];
    int tid = threadIdx.x;
    int chunk = (E + gridDim.x - 1) / gridDim.x;
    int s0 = blockIdx.x * chunk;
    int s1 = min(s0 + chunk, E);
    lh[tid] = 0;
    __syncthreads();
    for (int i = s0 + tid; i < s1; i += 256) atomicAdd(&lh[dst[i] >> 8], 1);
    __syncthreads();
    int c = lh[tid];
    lbase[tid] = c ? atomicAdd(&ccur[tid], c) : 0;
    __syncthreads();
    lh[tid] = 0;                       // reuse as local cursor
    __syncthreads();
    for (int i = s0 + tid; i < s1; i += 256) {
        int t = dst[i];
        int b = t >> 8;
        int r = atomicAdd(&lh[b], 1);
        int2 v; v.x = src[i]; v.y = t;
        part[lbase[b] + r] = v;
    }
}

// one block per coarse bin: per-node LDS count + scan -> rs, d, and final CSR est
__global__ __launch_bounds__(256) void bin_csr(const int2* __restrict__ part,
                                               const int* __restrict__ cbase,
                                               int* __restrict__ rs, float* __restrict__ d,
                                               int2* __restrict__ est, int N) {
    __shared__ int lcnt[256], s[256], lcur[256];
    int tid = threadIdx.x;
    int t0 = blockIdx.x << 8;
    int e0 = cbase[blockIdx.x], e1 = cbase[blockIdx.x + 1];
    lcnt[tid] = 0;
    __syncthreads();
    for (int i = e0 + tid; i < e1; i += 256) atomicAdd(&lcnt[part[i].y - t0], 1);
    __syncthreads();
    int v = lcnt[tid];
    s[tid] = v;
    __syncthreads();
    #pragma unroll
    for (int off = 1; off < 256; off <<= 1) {
        int o = (tid >= off) ? s[tid - off] : 0;
        __syncthreads();
        s[tid] += o;
        __syncthreads();
    }
    int excl = s[tid] - v;
    int node = t0 + tid;
    if (node < N) {
        rs[node] = e0 + excl;
        d[node] = rsqrtf(fmaxf((float)v, 1.0f));
    }
    lcur[tid] = e0 + excl;
    __syncthreads();
    for (int i = e0 + tid; i < e1; i += 256) {
        int2 e = part[i];
        int slot = atomicAdd(&lcur[e.y - t0], 1);
        est[slot] = e;
    }
}

// w [64][256] fp32 -> bf16
__global__ void cvt_w(const float* __restrict__ w, short* __restrict__ wb) {
    int i = blockIdx.x * blockDim.x + threadIdx.x;
    if (i < 64 * 256) wb[i] = f2bf(w[i]);
}

// per-CSR-slot: epack = (src, coef) with coef = tanh(a[t]+b[s]+gb)*d[t]*d[s]
__global__ void edge_coef(const int2* __restrict__ est,
                          const float* __restrict__ a, const float* __restrict__ b,
                          const float* __restrict__ d, const float* __restrict__ gbp,
                          int layer, int2* __restrict__ epack, int E) {
    int i = blockIdx.x * blockDim.x + threadIdx.x;
    if (i < E) {
        int2 e = est[i];
        float c = tanhf(a[e.y] + b[e.x] + gbp[layer]) * d[e.y] * d[e.x];
        int2 o; o.x = e.x; o.y = __float_as_int(c);
        epack[i] = o;
    }
}

// x0 = relu(h @ w^T + b); fused layer-0 gate dots. LDS-staged A (coalesced).
// MFMA 16x16x32 bf16. A: [m=lane&15][k=quad*8+j]; D: col=lane&15, row=quad*4+reg.
#define LROW 264   // LDS row stride in shorts (256 + 8 pad): 528 B, 16B-aligned
__global__ __launch_bounds__(256) void t1_mfma(
    const float* __restrict__ h, const short* __restrict__ wb,
    const float* __restrict__ t1b, const float* __restrict__ gw,
    float* __restrict__ XA, float* __restrict__ ga, float* __restrict__ gbv, int N)
{
    __shared__ short lh[4][16 * LROW];
    int wave = threadIdx.x >> 6;
    int lane = threadIdx.x & 63;
    int l15 = lane & 15, quad = lane >> 4;
    int M0 = (blockIdx.x * 4 + wave) * 16;
    if (M0 >= N) return;
    int rlim = N - M0;                         // rows valid in this tile (<=16)

    short* myl = lh[wave];
    const float* hb = h + (size_t)M0 * 256;
    #pragma unroll
    for (int r = 0; r < 16; ++r) {
        if (r < rlim) {
            float4 v = *(const float4*)&hb[(size_t)r * 256 + lane * 4];
            bf16x4 sv;
            sv[0] = f2bf(v.x); sv[1] = f2bf(v.y); sv[2] = f2bf(v.z); sv[3] = f2bf(v.w);
            *(bf16x4*)&myl[r * LROW + lane * 4] = sv;
        }
    }

    f32x4 acc[4];
    #pragma unroll
    for (int nt = 0; nt < 4; ++nt) acc[nt] = (f32x4){0.f, 0.f, 0.f, 0.f};

    const short* wq = wb + quad * 8;
    #pragma unroll
    for (int kc = 0; kc < 256; kc += 32) {
        bf16x8 af = *(const bf16x8*)&myl[l15 * LROW + kc + quad * 8];
        #pragma unroll
        for (int nt = 0; nt < 4; ++nt) {
            bf16x8 bf = *(const bf16x8*)(wq + (size_t)(nt * 16 + l15) * 256 + kc);
            acc[nt] = __builtin_amdgcn_mfma_f32_16x16x32_bf16(af, bf, acc[nt], 0, 0, 0);
        }
    }

    float pa[4] = {0.f, 0.f, 0.f, 0.f};
    float pb[4] = {0.f, 0.f, 0.f, 0.f};
    #pragma unroll
    for (int nt = 0; nt < 4; ++nt) {
        int n = nt * 16 + l15;
        float bias = t1b[n];
        float gd = gw[n], gs = gw[64 + n];
        #pragma unroll
        for (int r = 0; r < 4; ++r) {
            int row = quad * 4 + r;
            if (row < rlim) {
                float x = fmaxf(acc[nt][r] + bias, 0.f);
                XA[(size_t)(M0 + row) * 64 + n] = x;
                pa[r] += x * gd;
                pb[r] += x * gs;
            }
        }
    }
    #pragma unroll
    for (int off = 1; off < 16; off <<= 1) {
        #pragma unroll
        for (int r = 0; r < 4; ++r) {
            pa[r] += __shfl_xor(pa[r], off, 64);
            pb[r] += __shfl_xor(pb[r], off, 64);
        }
    }
    if (l15 == 0) {
        #pragma unroll
        for (int r = 0; r < 4; ++r) {
            int row = quad * 4 + r;
            if (row < rlim) {
                ga[M0 + row] = pa[r];
                gbv[M0 + row] = pb[r];
            }
        }
    }
}

// One wave per dst node, 4 edge-groups x 16 feature-quads (float4/lane):
// x_next[t] = EPS*raw[t] + sum_e coef(e) * x_cur[src(e)];
// epack = (src, coef_bits): one 8B load per edge in the hot loop.
// Optionally fuses next layer's gate dots from the freshly computed row.
__global__ __launch_bounds__(256) void gather4(
    const int* __restrict__ rs, const int2* __restrict__ epack,
    const float* __restrict__ xc, const float* __restrict__ raw,
    float* __restrict__ xn, const float* __restrict__ gw_next,
    float* __restrict__ ga_next, float* __restrict__ gb_next, int N)
{
    int tid = threadIdx.x;
    int t = blockIdx.x * 4 + (tid >> 6);
    if (t >= N) return;
    int lane = tid & 63;
    int g = lane >> 4;        // edge group 0..3
    int q = lane & 15;        // feature quad; features 4q..4q+3
    int beg = rs[t], end = rs[t + 1];

    float ax = 0.f, ay = 0.f, az = 0.f, aw = 0.f;
    if (g == 0) {
        float4 rv = *(const float4*)&raw[(size_t)t * 64 + q * 4];
        ax = EPS * rv.x; ay = EPS * rv.y; az = EPS * rv.z; aw = EPS * rv.w;
    }

    int i = beg + g;
    // 2x unrolled: two independent edges in flight per group
    for (; i + 4 < end; i += 8) {
        int2 e0 = epack[i];
        int2 e1 = epack[i + 4];
        float c0 = __int_as_float(e0.y);
        float c1 = __int_as_float(e1.y);
        float4 x0 = *(const float4*)&xc[(size_t)e0.x * 64 + q * 4];
        float4 x1 = *(const float4*)&xc[(size_t)e1.x * 64 + q * 4];
        ax += c0 * x0.x + c1 * x1.x;
        ay += c0 * x0.y + c1 * x1.y;
        az += c0 * x0.z + c1 * x1.z;
        aw += c0 * x0.w + c1 * x1.w;
    }
    if (i < end) {
        int2 e0 = epack[i];
        float c0 = __int_as_float(e0.y);
        float4 x0 = *(const float4*)&xc[(size_t)e0.x * 64 + q * 4];
        ax += c0 * x0.x; ay += c0 * x0.y; az += c0 * x0.z; aw += c0 * x0.w;
    }

    // reduce across the 4 edge groups (lanes differing in bits 4,5)
    #pragma unroll
    for (int off = 16; off < 64; off <<= 1) {
        ax += __shfl_xor(ax, off, 64);
        ay += __shfl_xor(ay, off, 64);
        az += __shfl_xor(az, off, 64);
        aw += __shfl_xor(aw, off, 64);
    }
    if (g == 0) {
        float4 o; o.x = ax; o.y = ay; o.z = az; o.w = aw;
        *(float4*)&xn[(size_t)t * 64 + q * 4] = o;
    }

    if (gw_next) {
        float4 gd = *(const float4*)&gw_next[q * 4];
        float4 gs = *(const float4*)&gw_next[64 + q * 4];
        float av = ax * gd.x + ay * gd.y + az * gd.z + aw * gd.w;
        float bv = ax * gs.x + ay * gs.y + az * gs.z + aw * gs.w;
        #pragma unroll
        for (int off = 1; off < 16; off <<= 1) {
            av += __shfl_xor(av, off, 64);
            bv += __shfl_xor(bv, off, 64);
        }
        if (lane == 0) { ga_next[t] = av; gb_next[t] = bv; }
    }
}

// logits = x @ t2_w^T + t2_b, then log_softmax over 16; thread per node
__global__ void out_logsoftmax(const float* __restrict__ x, const float* __restrict__ w,
                               const float* __restrict__ b, float* __restrict__ out, int N) {
    int n = blockIdx.x * blockDim.x + threadIdx.x;
    if (n >= N) return;
    float xi[64];
    const float4* xr = (const float4*)&x[(size_t)n * 64];
    #pragma unroll
    for (int k = 0; k < 16; ++k) {
        float4 v = xr[k];
        xi[4 * k + 0] = v.x; xi[4 * k + 1] = v.y; xi[4 * k + 2] = v.z; xi[4 * k + 3] = v.w;
    }
    float logits[16];
    float mx = -1e30f;
    #pragma unroll
    for (int j = 0; j < 16; ++j) {
        const float4* wr = (const float4*)&w[j * 64];
        float acc = b[j];
        #pragma unroll
        for (int k = 0; k < 16; ++k) {
            float4 wv = wr[k];
            acc += xi[4 * k + 0] * wv.x + xi[4 * k + 1] * wv.y
                 + xi[4 * k + 2] * wv.z + xi[4 * k + 3] * wv.w;
        }
        logits[j] = acc;
        mx = fmaxf(mx, acc);
    }
    float sum = 0.0f;
    #pragma unroll
    for (int j = 0; j < 16; ++j) sum += expf(logits[j] - mx);
    float lse = mx + logf(sum);
    #pragma unroll
    for (int j = 0; j < 16; ++j) out[(size_t)n * 16 + j] = logits[j] - lse;
}

extern "C" void kernel_launch(void* const* d_in, const int* in_sizes, int n_in,
                              void* d_out, int out_size, void* d_ws, size_t ws_size,
                              hipStream_t stream) {
    const float* h    = (const float*)d_in[0];
    const int*   src  = (const int*)d_in[1];
    const int*   dst  = (const int*)d_in[2];
    const float* t1w  = (const float*)d_in[3];
    const float* t1b  = (const float*)d_in[4];
    const float* gw   = (const float*)d_in[5];   // [2, 128]
    const float* gbia = (const float*)d_in[6];   // [2]
    const float* t2w  = (const float*)d_in[7];   // [16, 64]
    const float* t2b  = (const float*)d_in[8];   // [16]
    float* out = (float*)d_out;

    const int N = in_sizes[0] / 256;
    const int E = in_sizes[1];
    const int NBIN = (N + 255) / 256;            // coarse bins (<=256)

    char* p = (char*)d_ws;
    float* XA    = (float*)p;           p += (size_t)N * 64 * 4;   // x0 (raw) -> x2
    float* XB    = (float*)p;           p += (size_t)N * 64 * 4;   // x1
    float* dco   = (float*)p;           p += (size_t)N * 4;
    float* ga0   = (float*)p;           p += (size_t)N * 4;
    float* gb0   = (float*)p;           p += (size_t)N * 4;
    float* ga1   = (float*)p;           p += (size_t)N * 4;
    float* gb1   = (float*)p;           p += (size_t)N * 4;
    int*   rs    = (int*)p;             p += (size_t)(N + 1) * 4;
    int*   chist = (int*)p;             p += 256 * 4;
    int*   cbase = (int*)p;             p += 257 * 4;
    int*   ccur  = (int*)p;             p += 256 * 4;
    p = (char*)(((size_t)p + 15) & ~(size_t)15);
    int2*  part  = (int2*)p;            p += (size_t)E * 8;        // binned edges; reused as epack
    int2*  est   = (int2*)p;            p += (size_t)E * 8;        // final CSR (src, dst)
    short* wbf   = (short*)p;
    int2*  epack = part;                                           // overlay (part dead after bin_csr)

    // ---- CSR build: binned counting sort; also emits rs[] and d[] ----
    hipMemsetAsync(chist, 0, 256 * 4, stream);
    coarse_hist<<<256, 256, 0, stream>>>(dst, chist, E);
    coarse_scan<<<1, 256, 0, stream>>>(chist, cbase, ccur, rs, NBIN, N, E);
    partition<<<256, 256, 0, stream>>>(src, dst, ccur, part, E);
    bin_csr<<<NBIN, 256, 0, stream>>>(part, cbase, rs, dco, est, N);

    // ---- t1 + relu (MFMA, LDS-staged) with fused layer-0 gate dots ----
    cvt_w<<<64, 256, 0, stream>>>(t1w, wbf);
    t1_mfma<<<(N + 63) / 64, 256, 0, stream>>>(h, wbf, t1b, gw, XA, ga0, gb0, N);

    // ---- layer 0 ----
    edge_coef<<<(E + 255) / 256, 256, 0, stream>>>(est, ga0, gb0, dco, gbia, 0, epack, E);
    gather4<<<(N + 3) / 4, 256, 0, stream>>>(rs, epack, XA, XA, XB, gw + 128, ga1, gb1, N);

    // ---- layer 1 ----
    edge_coef<<<(E + 255) / 256, 256, 0, stream>>>(est, ga1, gb1, dco, gbia, 1, epack, E);
    gather4<<<(N + 3) / 4, 256, 0, stream>>>(rs, epack, XB, XA, XA, nullptr, nullptr, nullptr, N);

    // ---- logits + log_softmax ----
    out_logsoftmax<<<(N + 255) / 256, 256, 0, stream>>>(XA, t2w, t2b, out, N);
}

// Round 7
// 261.930 us; speedup vs baseline: 1.2192x; 1.0551x over previous
//
#include <hip/hip_runtime.h>
#include <math.h>

#define EPS 0.3f

typedef __attribute__((ext_vector_type(8))) short bf16x8;
typedef __attribute__((ext_vector_type(4))) short bf16x4;
typedef __attribute__((ext_vector_type(4))) float f32x4;

__device__ __forceinline__ short f2bf(float f) {
    union { float f; unsigned u; } v; v.f = f;
    unsigned r = v.u + 0x7FFFu + ((v.u >> 16) & 1u);  // RNE
    return (short)(r >> 16);
}
__device__ __forceinline__ float bf2f(short s) {
    union { unsigned u; float f; } v;
    v.u = ((unsigned)(unsigned short)s) << 16;
    return v.f;
}

// ---- CSR build: two-level binned counting sort (bins = dst>>8) ----

// per-block LDS histogram of dst>>8, merged into chist.
// Blocks 0..63 additionally convert w (64*256 fp32->bf16), 1 elem/thread.
__global__ __launch_bounds__(256) void coarse_hist(const int* __restrict__ dst,
                                                   int* __restrict__ chist, int E,
                                                   const float* __restrict__ w,
                                                   short* __restrict__ wb) {
    if (blockIdx.x < 64) {
        int i = blockIdx.x * 256 + threadIdx.x;
        wb[i] = f2bf(w[i]);
    }
    __shared__ int lh[256];
    lh[threadIdx.x] = 0;
    __syncthreads();
    for (int i = blockIdx.x * 256 + threadIdx.x; i < E; i += gridDim.x * 256)
        atomicAdd(&lh[dst[i] >> 8], 1);
    __syncthreads();
    int v = lh[threadIdx.x];
    if (v) atomicAdd(&chist[threadIdx.x], v);
}

// single-block exclusive scan of chist -> cbase, ccur; rs[N]=E
__global__ void coarse_scan(const int* __restrict__ chist, int* __restrict__ cbase,
                            int* __restrict__ ccur, int* __restrict__ rs,
                            int NBIN, int N, int E) {
    __shared__ int tmp[256];
    int tid = threadIdx.x;
    int v = (tid < NBIN) ? chist[tid] : 0;
    tmp[tid] = v;
    __syncthreads();
    #pragma unroll
    for (int off = 1; off < 256; off <<= 1) {
        int o = (tid >= off) ? tmp[tid - off] : 0;
        __syncthreads();
        tmp[tid] += o;
        __syncthreads();
    }
    if (tid < NBIN) { cbase[tid] = tmp[tid] - v; ccur[tid] = tmp[tid] - v; }
    if (tid == NBIN - 1) cbase[NBIN] = tmp[tid];
    if (tid == 0) rs[N] = E;
}

// partition edges into coarse-bin-grouped order: per-block LDS hist ->
// bulk range reservation -> grouped writes (good line locality)
__global__ __launch_bounds__(256) void partition(const int* __restrict__ src,
                                                 const int* __restrict__ dst,
                                                 int* __restrict__ ccur,
                                                 int2* __restrict__ part, int E) {
    __shared__ int lh[256];
    __shared__ int lbase[256];
    int tid = threadIdx.x;
    int chunk = (E + gridDim.x - 1) / gridDim.x;
    int s0 = blockIdx.x * chunk;
    int s1 = min(s0 + chunk, E);
    lh[tid] = 0;
    __syncthreads();
    for (int i = s0 + tid; i < s1; i += 256) atomicAdd(&lh[dst[i] >> 8], 1);
    __syncthreads();
    int c = lh[tid];
    lbase[tid] = c ? atomicAdd(&ccur[tid], c) : 0;
    __syncthreads();
    lh[tid] = 0;                       // reuse as local cursor
    __syncthreads();
    for (int i = s0 + tid; i < s1; i += 256) {
        int t = dst[i];
        int b = t >> 8;
        int r = atomicAdd(&lh[b], 1);
        int2 v; v.x = src[i]; v.y = t;
        part[lbase[b] + r] = v;
    }
}

// one block per coarse bin: per-node LDS count + scan -> rs, d, and final CSR est
__global__ __launch_bounds__(256) void bin_csr(const int2* __restrict__ part,
                                               const int* __restrict__ cbase,
                                               int* __restrict__ rs, float* __restrict__ d,
                                               int2* __restrict__ est, int N) {
    __shared__ int lcnt[256], s[256], lcur[256];
    int tid = threadIdx.x;
    int t0 = blockIdx.x << 8;
    int e0 = cbase[blockIdx.x], e1 = cbase[blockIdx.x + 1];
    lcnt[tid] = 0;
    __syncthreads();
    for (int i = e0 + tid; i < e1; i += 256) atomicAdd(&lcnt[part[i].y - t0], 1);
    __syncthreads();
    int v = lcnt[tid];
    s[tid] = v;
    __syncthreads();
    #pragma unroll
    for (int off = 1; off < 256; off <<= 1) {
        int o = (tid >= off) ? s[tid - off] : 0;
        __syncthreads();
        s[tid] += o;
        __syncthreads();
    }
    int excl = s[tid] - v;
    int node = t0 + tid;
    if (node < N) {
        rs[node] = e0 + excl;
        d[node] = rsqrtf(fmaxf((float)v, 1.0f));
    }
    lcur[tid] = e0 + excl;
    __syncthreads();
    for (int i = e0 + tid; i < e1; i += 256) {
        int2 e = part[i];
        int slot = atomicAdd(&lcur[e.y - t0], 1);
        est[slot] = e;
    }
}

// per-CSR-slot: epack = (src, coef) with coef = tanh(a[t]+b[s]+gb)*d[t]*d[s]
__global__ void edge_coef(const int2* __restrict__ est,
                          const float* __restrict__ a, const float* __restrict__ b,
                          const float* __restrict__ d, const float* __restrict__ gbp,
                          int layer, int2* __restrict__ epack, int E) {
    int i = blockIdx.x * blockDim.x + threadIdx.x;
    if (i < E) {
        int2 e = est[i];
        float c = tanhf(a[e.y] + b[e.x] + gbp[layer]) * d[e.y] * d[e.x];
        int2 o; o.x = e.x; o.y = __float_as_int(c);
        epack[i] = o;
    }
}

// x0 = relu(h @ w^T + b); fused layer-0 gate dots; writes fp32 + bf16 copies.
// MFMA 16x16x32 bf16. A: [m=lane&15][k=quad*8+j]; D: col=lane&15, row=quad*4+reg.
#define LROW 264   // LDS row stride in shorts (256 + 8 pad): 528 B, 16B-aligned
__global__ __launch_bounds__(256) void t1_mfma(
    const float* __restrict__ h, const short* __restrict__ wb,
    const float* __restrict__ t1b, const float* __restrict__ gw,
    float* __restrict__ XA, short* __restrict__ XAh,
    float* __restrict__ ga, float* __restrict__ gbv, int N)
{
    __shared__ short lh[4][16 * LROW];
    int wave = threadIdx.x >> 6;
    int lane = threadIdx.x & 63;
    int l15 = lane & 15, quad = lane >> 4;
    int M0 = (blockIdx.x * 4 + wave) * 16;
    if (M0 >= N) return;
    int rlim = N - M0;                         // rows valid in this tile (<=16)

    short* myl = lh[wave];
    const float* hb = h + (size_t)M0 * 256;
    #pragma unroll
    for (int r = 0; r < 16; ++r) {
        if (r < rlim) {
            float4 v = *(const float4*)&hb[(size_t)r * 256 + lane * 4];
            bf16x4 sv;
            sv[0] = f2bf(v.x); sv[1] = f2bf(v.y); sv[2] = f2bf(v.z); sv[3] = f2bf(v.w);
            *(bf16x4*)&myl[r * LROW + lane * 4] = sv;
        }
    }

    f32x4 acc[4];
    #pragma unroll
    for (int nt = 0; nt < 4; ++nt) acc[nt] = (f32x4){0.f, 0.f, 0.f, 0.f};

    const short* wq = wb + quad * 8;
    #pragma unroll
    for (int kc = 0; kc < 256; kc += 32) {
        bf16x8 af = *(const bf16x8*)&myl[l15 * LROW + kc + quad * 8];
        #pragma unroll
        for (int nt = 0; nt < 4; ++nt) {
            bf16x8 bf = *(const bf16x8*)(wq + (size_t)(nt * 16 + l15) * 256 + kc);
            acc[nt] = __builtin_amdgcn_mfma_f32_16x16x32_bf16(af, bf, acc[nt], 0, 0, 0);
        }
    }

    float pa[4] = {0.f, 0.f, 0.f, 0.f};
    float pb[4] = {0.f, 0.f, 0.f, 0.f};
    #pragma unroll
    for (int nt = 0; nt < 4; ++nt) {
        int n = nt * 16 + l15;
        float bias = t1b[n];
        float gd = gw[n], gs = gw[64 + n];
        #pragma unroll
        for (int r = 0; r < 4; ++r) {
            int row = quad * 4 + r;
            if (row < rlim) {
                float x = fmaxf(acc[nt][r] + bias, 0.f);
                size_t o = (size_t)(M0 + row) * 64 + n;
                XA[o] = x;
                XAh[o] = f2bf(x);
                pa[r] += x * gd;
                pb[r] += x * gs;
            }
        }
    }
    #pragma unroll
    for (int off = 1; off < 16; off <<= 1) {
        #pragma unroll
        for (int r = 0; r < 4; ++r) {
            pa[r] += __shfl_xor(pa[r], off, 64);
            pb[r] += __shfl_xor(pb[r], off, 64);
        }
    }
    if (l15 == 0) {
        #pragma unroll
        for (int r = 0; r < 4; ++r) {
            int row = quad * 4 + r;
            if (row < rlim) {
                ga[M0 + row] = pa[r];
                gbv[M0 + row] = pb[r];
            }
        }
    }
}

// One wave per dst node, 8 edge-groups x 8 feature-octets (bf16x8/lane):
// x_next[t] = EPS*raw[t] + sum_e coef(e) * xbf16[src(e)]; 16 edges in flight.
// Outputs fp32 and/or bf16; optionally fuses next layer's gate dots.
__global__ __launch_bounds__(256) void gather8(
    const int* __restrict__ rs, const int2* __restrict__ epack,
    const short* __restrict__ xch, const float* __restrict__ raw,
    float* __restrict__ xnf, short* __restrict__ xnh,
    const float* __restrict__ gw_next, float* __restrict__ ga_next,
    float* __restrict__ gb_next, int N)
{
    int tid = threadIdx.x;
    int t = blockIdx.x * 4 + (tid >> 6);
    if (t >= N) return;
    int lane = tid & 63;
    int g = lane >> 3;        // edge group 0..7
    int l = lane & 7;         // feature octet; features 8l..8l+7
    int beg = rs[t], end = rs[t + 1];

    float acc[8];
    #pragma unroll
    for (int k = 0; k < 8; ++k) acc[k] = 0.f;
    if (g == 0) {
        float4 r0 = *(const float4*)&raw[(size_t)t * 64 + l * 8];
        float4 r1 = *(const float4*)&raw[(size_t)t * 64 + l * 8 + 4];
        acc[0] = EPS * r0.x; acc[1] = EPS * r0.y; acc[2] = EPS * r0.z; acc[3] = EPS * r0.w;
        acc[4] = EPS * r1.x; acc[5] = EPS * r1.y; acc[6] = EPS * r1.z; acc[7] = EPS * r1.w;
    }

    int i = beg + g;
    // 2x unrolled: two independent edges per group in flight
    for (; i + 8 < end; i += 16) {
        int2 e0 = epack[i];
        int2 e1 = epack[i + 8];
        float c0 = __int_as_float(e0.y);
        float c1 = __int_as_float(e1.y);
        bf16x8 x0 = *(const bf16x8*)&xch[(size_t)e0.x * 64 + l * 8];
        bf16x8 x1 = *(const bf16x8*)&xch[(size_t)e1.x * 64 + l * 8];
        #pragma unroll
        for (int k = 0; k < 8; ++k) acc[k] += c0 * bf2f(x0[k]) + c1 * bf2f(x1[k]);
    }
    if (i < end) {
        int2 e0 = epack[i];
        float c0 = __int_as_float(e0.y);
        bf16x8 x0 = *(const bf16x8*)&xch[(size_t)e0.x * 64 + l * 8];
        #pragma unroll
        for (int k = 0; k < 8; ++k) acc[k] += c0 * bf2f(x0[k]);
    }

    // reduce across the 8 edge groups (lanes differing in bits 3,4,5)
    #pragma unroll
    for (int off = 8; off < 64; off <<= 1) {
        #pragma unroll
        for (int k = 0; k < 8; ++k) acc[k] += __shfl_xor(acc[k], off, 64);
    }

    if (g == 0) {
        if (xnf) {
            float4 o0, o1;
            o0.x = acc[0]; o0.y = acc[1]; o0.z = acc[2]; o0.w = acc[3];
            o1.x = acc[4]; o1.y = acc[5]; o1.z = acc[6]; o1.w = acc[7];
            *(float4*)&xnf[(size_t)t * 64 + l * 8] = o0;
            *(float4*)&xnf[(size_t)t * 64 + l * 8 + 4] = o1;
        }
        if (xnh) {
            bf16x8 o;
            #pragma unroll
            for (int k = 0; k < 8; ++k) o[k] = f2bf(acc[k]);
            *(bf16x8*)&xnh[(size_t)t * 64 + l * 8] = o;
        }
        if (gw_next) {
            float av = 0.f, bv = 0.f;
            #pragma unroll
            for (int k = 0; k < 8; ++k) {
                av += acc[k] * gw_next[l * 8 + k];
                bv += acc[k] * gw_next[64 + l * 8 + k];
            }
            #pragma unroll
            for (int off = 1; off < 8; off <<= 1) {
                av += __shfl_xor(av, off, 64);
                bv += __shfl_xor(bv, off, 64);
            }
            if (l == 0) { ga_next[t] = av; gb_next[t] = bv; }
        }
    }
}

// logits = x @ t2_w^T + t2_b, then log_softmax over 16; thread per node
__global__ void out_logsoftmax(const float* __restrict__ x, const float* __restrict__ w,
                               const float* __restrict__ b, float* __restrict__ out, int N) {
    int n = blockIdx.x * blockDim.x + threadIdx.x;
    if (n >= N) return;
    float xi[64];
    const float4* xr = (const float4*)&x[(size_t)n * 64];
    #pragma unroll
    for (int k = 0; k < 16; ++k) {
        float4 v = xr[k];
        xi[4 * k + 0] = v.x; xi[4 * k + 1] = v.y; xi[4 * k + 2] = v.z; xi[4 * k + 3] = v.w;
    }
    float logits[16];
    float mx = -1e30f;
    #pragma unroll
    for (int j = 0; j < 16; ++j) {
        const float4* wr = (const float4*)&w[j * 64];
        float acc = b[j];
        #pragma unroll
        for (int k = 0; k < 16; ++k) {
            float4 wv = wr[k];
            acc += xi[4 * k + 0] * wv.x + xi[4 * k + 1] * wv.y
                 + xi[4 * k + 2] * wv.z + xi[4 * k + 3] * wv.w;
        }
        logits[j] = acc;
        mx = fmaxf(mx, acc);
    }
    float sum = 0.0f;
    #pragma unroll
    for (int j = 0; j < 16; ++j) sum += expf(logits[j] - mx);
    float lse = mx + logf(sum);
    #pragma unroll
    for (int j = 0; j < 16; ++j) out[(size_t)n * 16 + j] = logits[j] - lse;
}

extern "C" void kernel_launch(void* const* d_in, const int* in_sizes, int n_in,
                              void* d_out, int out_size, void* d_ws, size_t ws_size,
                              hipStream_t stream) {
    const float* h    = (const float*)d_in[0];
    const int*   src  = (const int*)d_in[1];
    const int*   dst  = (const int*)d_in[2];
    const float* t1w  = (const float*)d_in[3];
    const float* t1b  = (const float*)d_in[4];
    const float* gw   = (const float*)d_in[5];   // [2, 128]
    const float* gbia = (const float*)d_in[6];   // [2]
    const float* t2w  = (const float*)d_in[7];   // [16, 64]
    const float* t2b  = (const float*)d_in[8];   // [16]
    float* out = (float*)d_out;

    const int N = in_sizes[0] / 256;
    const int E = in_sizes[1];
    const int NBIN = (N + 255) / 256;            // coarse bins (<=256)

    char* p = (char*)d_ws;
    float* XA    = (float*)p;           p += (size_t)N * 64 * 4;   // x0 fp32 (raw) -> x2
    short* XAh   = (short*)p;           p += (size_t)N * 64 * 2;   // x0 bf16
    short* XBh   = (short*)p;           p += (size_t)N * 64 * 2;   // x1 bf16
    float* dco   = (float*)p;           p += (size_t)N * 4;
    float* ga0   = (float*)p;           p += (size_t)N * 4;
    float* gb0   = (float*)p;           p += (size_t)N * 4;
    float* ga1   = (float*)p;           p += (size_t)N * 4;
    float* gb1   = (float*)p;           p += (size_t)N * 4;
    int*   rs    = (int*)p;             p += (size_t)(N + 1) * 4;
    int*   chist = (int*)p;             p += 256 * 4;
    int*   cbase = (int*)p;             p += 257 * 4;
    int*   ccur  = (int*)p;             p += 256 * 4;
    p = (char*)(((size_t)p + 15) & ~(size_t)15);
    int2*  part  = (int2*)p;            p += (size_t)E * 8;        // binned edges; reused as epack
    int2*  est   = (int2*)p;            p += (size_t)E * 8;        // final CSR (src, dst)
    short* wbf   = (short*)p;
    int2*  epack = part;                                           // overlay (part dead after bin_csr)

    // ---- CSR build: binned counting sort; also emits rs[] and d[] ----
    hipMemsetAsync(chist, 0, 256 * 4, stream);
    coarse_hist<<<256, 256, 0, stream>>>(dst, chist, E, t1w, wbf);
    coarse_scan<<<1, 256, 0, stream>>>(chist, cbase, ccur, rs, NBIN, N, E);
    partition<<<256, 256, 0, stream>>>(src, dst, ccur, part, E);
    bin_csr<<<NBIN, 256, 0, stream>>>(part, cbase, rs, dco, est, N);

    // ---- t1 + relu (MFMA, LDS-staged) with fused layer-0 gate dots ----
    t1_mfma<<<(N + 63) / 64, 256, 0, stream>>>(h, wbf, t1b, gw, XA, XAh, ga0, gb0, N);

    // ---- layer 0: x1(bf16) = EPS*x0 + gather(x0); fused layer-1 gate dots ----
    edge_coef<<<(E + 255) / 256, 256, 0, stream>>>(est, ga0, gb0, dco, gbia, 0, epack, E);
    gather8<<<(N + 3) / 4, 256, 0, stream>>>(rs, epack, XAh, XA, nullptr, XBh,
                                             gw + 128, ga1, gb1, N);

    // ---- layer 1: x2(fp32) = EPS*x0 + gather(x1) ----
    edge_coef<<<(E + 255) / 256, 256, 0, stream>>>(est, ga1, gb1, dco, gbia, 1, epack, E);
    gather8<<<(N + 3) / 4, 256, 0, stream>>>(rs, epack, XBh, XA, XA, nullptr,
                                             nullptr, nullptr, nullptr, N);

    // ---- logits + log_softmax ----
    out_logsoftmax<<<(N + 255) / 256, 256, 0, stream>>>(XA, t2w, t2b, out, N);
}

// Round 8
// 234.162 us; speedup vs baseline: 1.3638x; 1.1186x over previous
//
#include <hip/hip_runtime.h>
#include <math.h>

#define EPS 0.3f

typedef __attribute__((ext_vector_type(8))) short bf16x8;
typedef __attribute__((ext_vector_type(4))) short bf16x4;
typedef __attribute__((ext_vector_type(4))) float f32x4;

__device__ __forceinline__ short f2bf(float f) {
    union { float f; unsigned u; } v; v.f = f;
    unsigned r = v.u + 0x7FFFu + ((v.u >> 16) & 1u);  // RNE
    return (short)(r >> 16);
}
__device__ __forceinline__ float bf2f(short s) {
    union { unsigned u; float f; } v;
    v.u = ((unsigned)(unsigned short)s) << 16;
    return v.f;
}

// ---- CSR build: two-level binned counting sort (bins = dst>>8) ----

// per-block LDS histogram of dst>>8, merged into chist.
// Blocks 0..63 additionally convert w (64*256 fp32->bf16), 1 elem/thread.
__global__ __launch_bounds__(256) void coarse_hist(const int* __restrict__ dst,
                                                   int* __restrict__ chist, int E,
                                                   const float* __restrict__ w,
                                                   short* __restrict__ wb) {
    if (blockIdx.x < 64) {
        int i = blockIdx.x * 256 + threadIdx.x;
        wb[i] = f2bf(w[i]);
    }
    __shared__ int lh[256];
    lh[threadIdx.x] = 0;
    __syncthreads();
    for (int i = blockIdx.x * 256 + threadIdx.x; i < E; i += gridDim.x * 256)
        atomicAdd(&lh[dst[i] >> 8], 1);
    __syncthreads();
    int v = lh[threadIdx.x];
    if (v) atomicAdd(&chist[threadIdx.x], v);
}

// single-block exclusive scan of chist -> cbase, ccur; rs[N]=E
__global__ void coarse_scan(const int* __restrict__ chist, int* __restrict__ cbase,
                            int* __restrict__ ccur, int* __restrict__ rs,
                            int NBIN, int N, int E) {
    __shared__ int tmp[256];
    int tid = threadIdx.x;
    int v = (tid < NBIN) ? chist[tid] : 0;
    tmp[tid] = v;
    __syncthreads();
    #pragma unroll
    for (int off = 1; off < 256; off <<= 1) {
        int o = (tid >= off) ? tmp[tid - off] : 0;
        __syncthreads();
        tmp[tid] += o;
        __syncthreads();
    }
    if (tid < NBIN) { cbase[tid] = tmp[tid] - v; ccur[tid] = tmp[tid] - v; }
    if (tid == NBIN - 1) cbase[NBIN] = tmp[tid];
    if (tid == 0) rs[N] = E;
}

// partition edges into coarse-bin-grouped order: per-block LDS hist ->
// bulk range reservation -> grouped writes (good line locality)
__global__ __launch_bounds__(256) void partition(const int* __restrict__ src,
                                                 const int* __restrict__ dst,
                                                 int* __restrict__ ccur,
                                                 int2* __restrict__ part, int E) {
    __shared__ int lh[256];
    __shared__ int lbase[256];
    int tid = threadIdx.x;
    int chunk = (E + gridDim.x - 1) / gridDim.x;
    int s0 = blockIdx.x * chunk;
    int s1 = min(s0 + chunk, E);
    lh[tid] = 0;
    __syncthreads();
    for (int i = s0 + tid; i < s1; i += 256) atomicAdd(&lh[dst[i] >> 8], 1);
    __syncthreads();
    int c = lh[tid];
    lbase[tid] = c ? atomicAdd(&ccur[tid], c) : 0;
    __syncthreads();
    lh[tid] = 0;                       // reuse as local cursor
    __syncthreads();
    for (int i = s0 + tid; i < s1; i += 256) {
        int t = dst[i];
        int b = t >> 8;
        int r = atomicAdd(&lh[b], 1);
        int2 v; v.x = src[i]; v.y = t;
        part[lbase[b] + r] = v;
    }
}

// one block per coarse bin: per-node LDS count + scan -> rs, d, and CSR esrc
__global__ __launch_bounds__(256) void bin_csr(const int2* __restrict__ part,
                                               const int* __restrict__ cbase,
                                               int* __restrict__ rs, float* __restrict__ d,
                                               int* __restrict__ esrc, int N) {
    __shared__ int lcnt[256], s[256], lcur[256];
    int tid = threadIdx.x;
    int t0 = blockIdx.x << 8;
    int e0 = cbase[blockIdx.x], e1 = cbase[blockIdx.x + 1];
    lcnt[tid] = 0;
    __syncthreads();
    for (int i = e0 + tid; i < e1; i += 256) atomicAdd(&lcnt[part[i].y - t0], 1);
    __syncthreads();
    int v = lcnt[tid];
    s[tid] = v;
    __syncthreads();
    #pragma unroll
    for (int off = 1; off < 256; off <<= 1) {
        int o = (tid >= off) ? s[tid - off] : 0;
        __syncthreads();
        s[tid] += o;
        __syncthreads();
    }
    int excl = s[tid] - v;
    int node = t0 + tid;
    if (node < N) {
        rs[node] = e0 + excl;
        d[node] = rsqrtf(fmaxf((float)v, 1.0f));
    }
    lcur[tid] = e0 + excl;
    __syncthreads();
    for (int i = e0 + tid; i < e1; i += 256) {
        int2 e = part[i];
        int slot = atomicAdd(&lcur[e.y - t0], 1);
        esrc[slot] = e.x;
    }
}

// x0 = relu(h @ w^T + b); fused layer-0 gate dots; writes fp32 + bf16 copies,
// ga0 and bd0=(gb0, d). MFMA 16x16x32 bf16. A: [m=lane&15][k=quad*8+j];
// D: col=lane&15, row=quad*4+reg.
#define LROW 264   // LDS row stride in shorts (256 + 8 pad): 528 B, 16B-aligned
__global__ __launch_bounds__(256) void t1_mfma(
    const float* __restrict__ h, const short* __restrict__ wb,
    const float* __restrict__ t1b, const float* __restrict__ gw,
    const float* __restrict__ dco,
    float* __restrict__ XA, short* __restrict__ XAh,
    float* __restrict__ ga, float2* __restrict__ bd, int N)
{
    __shared__ short lh[4][16 * LROW];
    int wave = threadIdx.x >> 6;
    int lane = threadIdx.x & 63;
    int l15 = lane & 15, quad = lane >> 4;
    int M0 = (blockIdx.x * 4 + wave) * 16;
    if (M0 >= N) return;
    int rlim = N - M0;                         // rows valid in this tile (<=16)

    short* myl = lh[wave];
    const float* hb = h + (size_t)M0 * 256;
    #pragma unroll
    for (int r = 0; r < 16; ++r) {
        if (r < rlim) {
            float4 v = *(const float4*)&hb[(size_t)r * 256 + lane * 4];
            bf16x4 sv;
            sv[0] = f2bf(v.x); sv[1] = f2bf(v.y); sv[2] = f2bf(v.z); sv[3] = f2bf(v.w);
            *(bf16x4*)&myl[r * LROW + lane * 4] = sv;
        }
    }

    f32x4 acc[4];
    #pragma unroll
    for (int nt = 0; nt < 4; ++nt) acc[nt] = (f32x4){0.f, 0.f, 0.f, 0.f};

    const short* wq = wb + quad * 8;
    #pragma unroll
    for (int kc = 0; kc < 256; kc += 32) {
        bf16x8 af = *(const bf16x8*)&myl[l15 * LROW + kc + quad * 8];
        #pragma unroll
        for (int nt = 0; nt < 4; ++nt) {
            bf16x8 bf = *(const bf16x8*)(wq + (size_t)(nt * 16 + l15) * 256 + kc);
            acc[nt] = __builtin_amdgcn_mfma_f32_16x16x32_bf16(af, bf, acc[nt], 0, 0, 0);
        }
    }

    float pa[4] = {0.f, 0.f, 0.f, 0.f};
    float pb[4] = {0.f, 0.f, 0.f, 0.f};
    #pragma unroll
    for (int nt = 0; nt < 4; ++nt) {
        int n = nt * 16 + l15;
        float bias = t1b[n];
        float gd = gw[n], gs = gw[64 + n];
        #pragma unroll
        for (int r = 0; r < 4; ++r) {
            int row = quad * 4 + r;
            if (row < rlim) {
                float x = fmaxf(acc[nt][r] + bias, 0.f);
                size_t o = (size_t)(M0 + row) * 64 + n;
                XA[o] = x;
                XAh[o] = f2bf(x);
                pa[r] += x * gd;
                pb[r] += x * gs;
            }
        }
    }
    #pragma unroll
    for (int off = 1; off < 16; off <<= 1) {
        #pragma unroll
        for (int r = 0; r < 4; ++r) {
            pa[r] += __shfl_xor(pa[r], off, 64);
            pb[r] += __shfl_xor(pb[r], off, 64);
        }
    }
    if (l15 == 0) {
        #pragma unroll
        for (int r = 0; r < 4; ++r) {
            int row = quad * 4 + r;
            if (row < rlim) {
                ga[M0 + row] = pa[r];
                float2 v; v.x = pb[r]; v.y = dco[M0 + row];
                bd[M0 + row] = v;
            }
        }
    }
}

// Shared gather core: one wave per dst node, 8 edge-groups x 8 feature-octets.
// acc[k] = EPS*raw + sum_e tanh(a[t]+b[s]+gb)*d[t]*d[s] * xbf16[s]; after the
// xor-reduce every lane holds the full row (features (lane&7)*8+k).
__device__ __forceinline__ void gather_core(
    const int* __restrict__ rs, const int* __restrict__ esrc,
    const float* __restrict__ a, const float2* __restrict__ bd,
    const short* __restrict__ xch, const float* __restrict__ raw,
    float gbias, int t, int lane, float acc[8])
{
    int g = lane >> 3;        // edge group 0..7
    int l = lane & 7;         // feature octet
    int beg = rs[t], end = rs[t + 1];
    float at = a[t];
    float dt = bd[t].y;

    #pragma unroll
    for (int k = 0; k < 8; ++k) acc[k] = 0.f;
    if (g == 0) {
        float4 r0 = *(const float4*)&raw[(size_t)t * 64 + l * 8];
        float4 r1 = *(const float4*)&raw[(size_t)t * 64 + l * 8 + 4];
        acc[0] = EPS * r0.x; acc[1] = EPS * r0.y; acc[2] = EPS * r0.z; acc[3] = EPS * r0.w;
        acc[4] = EPS * r1.x; acc[5] = EPS * r1.y; acc[6] = EPS * r1.z; acc[7] = EPS * r1.w;
    }

    int i = beg + g;
    for (; i + 8 < end; i += 16) {
        int s0 = esrc[i];
        int s1 = esrc[i + 8];
        float2 bd0 = bd[s0];
        float2 bd1 = bd[s1];
        bf16x8 x0 = *(const bf16x8*)&xch[(size_t)s0 * 64 + l * 8];
        bf16x8 x1 = *(const bf16x8*)&xch[(size_t)s1 * 64 + l * 8];
        float c0 = tanhf(at + bd0.x + gbias) * dt * bd0.y;
        float c1 = tanhf(at + bd1.x + gbias) * dt * bd1.y;
        #pragma unroll
        for (int k = 0; k < 8; ++k) acc[k] += c0 * bf2f(x0[k]) + c1 * bf2f(x1[k]);
    }
    if (i < end) {
        int s0 = esrc[i];
        float2 bd0 = bd[s0];
        bf16x8 x0 = *(const bf16x8*)&xch[(size_t)s0 * 64 + l * 8];
        float c0 = tanhf(at + bd0.x + gbias) * dt * bd0.y;
        #pragma unroll
        for (int k = 0; k < 8; ++k) acc[k] += c0 * bf2f(x0[k]);
    }

    // reduce across the 8 edge groups (lanes differing in bits 3,4,5)
    #pragma unroll
    for (int off = 8; off < 64; off <<= 1) {
        #pragma unroll
        for (int k = 0; k < 8; ++k) acc[k] += __shfl_xor(acc[k], off, 64);
    }
}

// layer 0: writes x1 bf16 + next-layer gate dots (ga1, bd1=(gb1,d))
__global__ __launch_bounds__(256) void gather_mid(
    const int* __restrict__ rs, const int* __restrict__ esrc,
    const float* __restrict__ a, const float2* __restrict__ bd,
    const short* __restrict__ xch, const float* __restrict__ raw,
    const float* __restrict__ gbp, short* __restrict__ xnh,
    const float* __restrict__ gw_next, float* __restrict__ ga_next,
    float2* __restrict__ bd_next, int N)
{
    int tid = threadIdx.x;
    int t = blockIdx.x * 4 + (tid >> 6);
    if (t >= N) return;
    int lane = tid & 63;
    int g = lane >> 3, l = lane & 7;
    float acc[8];
    gather_core(rs, esrc, a, bd, xch, raw, gbp[0], t, lane, acc);

    if (g == 0) {
        bf16x8 o;
        #pragma unroll
        for (int k = 0; k < 8; ++k) o[k] = f2bf(acc[k]);
        *(bf16x8*)&xnh[(size_t)t * 64 + l * 8] = o;
    }
    // gate dots: all lanes have the full row; lanes of group 0 compute
    float av = 0.f, bv = 0.f;
    #pragma unroll
    for (int k = 0; k < 8; ++k) {
        av += acc[k] * gw_next[l * 8 + k];
        bv += acc[k] * gw_next[64 + l * 8 + k];
    }
    #pragma unroll
    for (int off = 1; off < 8; off <<= 1) {
        av += __shfl_xor(av, off, 64);
        bv += __shfl_xor(bv, off, 64);
    }
    if (lane == 0) {
        ga_next[t] = av;
        float2 v; v.x = bv; v.y = bd[t].y;
        bd_next[t] = v;
    }
}

// layer 1: fused t2 matmul + log_softmax; x2 never materialized.
// lane (g,l) computes logits j=2g,2g+1 partials over features 8l..8l+7.
__global__ __launch_bounds__(256) void gather_out(
    const int* __restrict__ rs, const int* __restrict__ esrc,
    const float* __restrict__ a, const float2* __restrict__ bd,
    const short* __restrict__ xch, const float* __restrict__ raw,
    const float* __restrict__ gbp, const float* __restrict__ t2w,
    const float* __restrict__ t2b, float* __restrict__ out, int N)
{
    int tid = threadIdx.x;
    int t = blockIdx.x * 4 + (tid >> 6);
    if (t >= N) return;
    int lane = tid & 63;
    int g = lane >> 3, l = lane & 7;
    float acc[8];
    gather_core(rs, esrc, a, bd, xch, raw, gbp[1], t, lane, acc);

    int j0 = 2 * g;
    const float* w0 = &t2w[(size_t)j0 * 64 + l * 8];
    const float* w1 = w0 + 64;
    float p0 = 0.f, p1 = 0.f;
    #pragma unroll
    for (int k = 0; k < 8; ++k) { p0 += acc[k] * w0[k]; p1 += acc[k] * w1[k]; }
    #pragma unroll
    for (int off = 1; off < 8; off <<= 1) {
        p0 += __shfl_xor(p0, off, 64);
        p1 += __shfl_xor(p1, off, 64);
    }
    float l0 = p0 + t2b[j0];
    float l1 = p1 + t2b[j0 + 1];
    float m = fmaxf(l0, l1);
    #pragma unroll
    for (int off = 8; off < 64; off <<= 1) m = fmaxf(m, __shfl_xor(m, off, 64));
    float s = __expf(l0 - m) + __expf(l1 - m);
    #pragma unroll
    for (int off = 8; off < 64; off <<= 1) s += __shfl_xor(s, off, 64);
    float lse = m + __logf(s);
    if (l == 0) {
        float2 o; o.x = l0 - lse; o.y = l1 - lse;
        *(float2*)&out[(size_t)t * 16 + j0] = o;
    }
}

extern "C" void kernel_launch(void* const* d_in, const int* in_sizes, int n_in,
                              void* d_out, int out_size, void* d_ws, size_t ws_size,
                              hipStream_t stream) {
    const float* h    = (const float*)d_in[0];
    const int*   src  = (const int*)d_in[1];
    const int*   dst  = (const int*)d_in[2];
    const float* t1w  = (const float*)d_in[3];
    const float* t1b  = (const float*)d_in[4];
    const float* gw   = (const float*)d_in[5];   // [2, 128]
    const float* gbia = (const float*)d_in[6];   // [2]
    const float* t2w  = (const float*)d_in[7];   // [16, 64]
    const float* t2b  = (const float*)d_in[8];   // [16]
    float* out = (float*)d_out;

    const int N = in_sizes[0] / 256;
    const int E = in_sizes[1];
    const int NBIN = (N + 255) / 256;            // coarse bins (<=256)

    char* p = (char*)d_ws;
    float*  XA    = (float*)p;          p += (size_t)N * 64 * 4;   // x0 fp32 (raw)
    short*  XAh   = (short*)p;          p += (size_t)N * 64 * 2;   // x0 bf16
    short*  XBh   = (short*)p;          p += (size_t)N * 64 * 2;   // x1 bf16
    float*  dco   = (float*)p;          p += (size_t)N * 4;
    float*  ga0   = (float*)p;          p += (size_t)N * 4;
    float*  ga1   = (float*)p;          p += (size_t)N * 4;
    float2* bd0   = (float2*)p;         p += (size_t)N * 8;        // (gb0, d)
    float2* bd1   = (float2*)p;         p += (size_t)N * 8;        // (gb1, d)
    int*    rs    = (int*)p;            p += (size_t)(N + 1) * 4;
    int*    chist = (int*)p;            p += 256 * 4;
    int*    cbase = (int*)p;            p += 257 * 4;
    int*    ccur  = (int*)p;            p += 256 * 4;
    p = (char*)(((size_t)p + 15) & ~(size_t)15);
    int2*   part  = (int2*)p;           p += (size_t)E * 8;        // binned (src,dst)
    int*    esrc  = (int*)p;            p += (size_t)E * 4;        // final CSR src
    short*  wbf   = (short*)p;

    // ---- CSR build: binned counting sort; also emits rs[] and d[] ----
    hipMemsetAsync(chist, 0, 256 * 4, stream);
    coarse_hist<<<256, 256, 0, stream>>>(dst, chist, E, t1w, wbf);
    coarse_scan<<<1, 256, 0, stream>>>(chist, cbase, ccur, rs, NBIN, N, E);
    partition<<<256, 256, 0, stream>>>(src, dst, ccur, part, E);
    bin_csr<<<NBIN, 256, 0, stream>>>(part, cbase, rs, dco, esrc, N);

    // ---- t1 + relu (MFMA) with fused layer-0 gate dots ----
    t1_mfma<<<(N + 63) / 64, 256, 0, stream>>>(h, wbf, t1b, gw, dco, XA, XAh, ga0, bd0, N);

    // ---- layer 0: x1(bf16) = EPS*x0 + gather(x0); fused layer-1 gate dots ----
    gather_mid<<<(N + 3) / 4, 256, 0, stream>>>(rs, esrc, ga0, bd0, XAh, XA, gbia,
                                                XBh, gw + 128, ga1, bd1, N);

    // ---- layer 1: fused gather + t2 + log_softmax ----
    gather_out<<<(N + 3) / 4, 256, 0, stream>>>(rs, esrc, ga1, bd1, XBh, XA, gbia,
                                                t2w, t2b, out, N);
}